// Round 3
// baseline (496.998 us; speedup 1.0000x reference)
//
#include <hip/hip_runtime.h>

// Problem constants (fixed by the reference setup_inputs()).
#define KK 27
#define PP 100000
#define C_IN 32
#define C_OUT 32
#define N_IN 200000
#define N_OUT 400000
#define PAIRS_PER_BLOCK 160   // 8 groups * 20 iterations; 100000/160 = 625 exact

// ---------------------------------------------------------------------------
// Kernel 1: out[n][c] = bias[c]  (float4-vectorized broadcast init)
// total float4 elements: N_OUT * 32 / 4 = 3,200,000
// ---------------------------------------------------------------------------
__global__ __launch_bounds__(256) void init_out_kernel(
    float4* __restrict__ out4, const float4* __restrict__ bias4) {
    int i = blockIdx.x * 256 + threadIdx.x;        // float4 index
    // channel of this float4 = (4*i) & 31  -> bias4 index = i & 7
    out4[i] = bias4[i & 7];
}

// ---------------------------------------------------------------------------
// Kernel 2: main rulebook kernel.
//   grid = (P/PAIRS_PER_BLOCK, K) = (625, 27)
//   block = 256 threads = 8 groups of 32 lanes
//   lane c (= tid & 31) owns output channel c; weight column in registers.
//   Each group handles pairs base, base+8, ..., base+8*19 (20 pairs).
//   NOTE: harness stages integer inputs as int32 ("integer -> const int*"),
//   NOT int64 as the reference dtype suggests. Reading them as long long
//   produced garbage indices -> OOB atomics -> core dump (round 2).
// ---------------------------------------------------------------------------
__global__ __launch_bounds__(256) void spconv_scatter_kernel(
    const float* __restrict__ feats,      // [N_IN, 32]
    const float* __restrict__ weight,     // [K, 32, 32]
    const int* __restrict__ pin,          // [K, P] int32
    const int* __restrict__ pout,         // [K, P] int32
    float* __restrict__ out)              // [N_OUT, 32]
{
    const int k   = blockIdx.y;
    const int c   = threadIdx.x & 31;
    const int grp = threadIdx.x >> 5;

    // Load this lane's weight column W[k][:, c] into registers (coalesced:
    // for fixed ci, lanes c=0..31 read 128B contiguous; L1-resident for all
    // 8 groups since k is block-uniform).
    const float* w = weight + k * (C_IN * C_OUT) + c;
    float wcol[C_IN];
#pragma unroll
    for (int ci = 0; ci < C_IN; ++ci) wcol[ci] = w[ci * C_OUT];

    const int* pin_k  = pin  + k * PP;
    const int* pout_k = pout + k * PP;

    const int base = blockIdx.x * PAIRS_PER_BLOCK + grp;

#pragma unroll 4
    for (int i = 0; i < PAIRS_PER_BLOCK / 8; ++i) {   // exactly 20 iterations
        const int p  = base + i * 8;
        const int ii = pin_k[p];
        const int io = pout_k[p];

        // Gather the feats row (broadcast across the 32-lane group -> one
        // 16B transaction per float4 per group).
        const float4* f4 = (const float4*)(feats + ii * 32);
        float acc = 0.0f;
#pragma unroll
        for (int j = 0; j < 8; ++j) {
            const float4 f = f4[j];
            acc = fmaf(f.x, wcol[4 * j + 0], acc);
            acc = fmaf(f.y, wcol[4 * j + 1], acc);
            acc = fmaf(f.z, wcol[4 * j + 2], acc);
            acc = fmaf(f.w, wcol[4 * j + 3], acc);
        }
        atomicAdd(out + io * 32 + c, acc);
    }
}

// ---------------------------------------------------------------------------
// Launch
// ---------------------------------------------------------------------------
extern "C" void kernel_launch(void* const* d_in, const int* in_sizes, int n_in,
                              void* d_out, int out_size, void* d_ws, size_t ws_size,
                              hipStream_t stream) {
    const float* feats  = (const float*)d_in[0];       // [N_IN, 32]
    const float* weight = (const float*)d_in[1];       // [K, 32, 32]
    const float* bias   = (const float*)d_in[2];       // [32]
    const int*   pin    = (const int*)d_in[3];         // [K, P] int32
    const int*   pout   = (const int*)d_in[4];         // [K, P] int32
    float*       out    = (float*)d_out;               // [N_OUT, 32]

    // 1) out = bias (also clears the 0xAA poison)
    const int n_f4 = N_OUT * C_OUT / 4;                // 3,200,000
    init_out_kernel<<<n_f4 / 256, 256, 0, stream>>>(
        (float4*)out, (const float4*)bias);

    // 2) gather-GEMM-scatter
    dim3 grid(PP / PAIRS_PER_BLOCK, KK);               // (625, 27)
    spconv_scatter_kernel<<<grid, 256, 0, stream>>>(
        feats, weight, pin, pout, out);
}